// Round 7
// baseline (121.915 us; speedup 1.0000x reference)
//
#include <hip/hip_runtime.h>
#include <math.h>

#define NS 32          // NSAMPLE
#define WPB 4          // waves per block
#define SCAN0 2048     // prefix length scanned in the dense phase
#define TSTRIDE 36     // transpose j-stride in dwords (mult of 4 -> b128-aligned)

// ---------------------------------------------------------------------------
// Per-WAVE output epilogue for one query m. Uses only this wave's LDS tile
// (sT, 32*TSTRIDE floats) and idx list (sIdxW, 32 ints). All LDS use is
// wave-internal: 64 lanes run in lockstep and the compiler inserts lgkmcnt
// for the write->read dependency, so NO __syncthreads needed. XOR swizzle
// (r ^ 4*(k&3)) makes transpose writes exactly 2-way banked (free, m136)
// while keeping reads 16B-aligned.
// ---------------------------------------------------------------------------
__device__ __forceinline__ void write_query(
    int m, int bb, bool empty, int lane,
    const int* sIdxW, float* sT,
    const float* __restrict__ xyz, const float* __restrict__ new_xyz,
    const float* __restrict__ new_xyz_r, const float* __restrict__ features,
    float real_t, float* __restrict__ out, int N_per, int C, int M_tot)
{
#pragma clang fp contract(off)
    const float* xb = xyz + (size_t)bb * N_per * 3;
    const int    j  = lane & 31;
    const size_t nf_base = (size_t)m * (3 + C) * NS;
    float* wout = out + (size_t)M_tot * (3 + C) * NS;
    float* iout = wout + (size_t)M_tot * NS;

    if (lane < NS) {
        const float qx = new_xyz[(size_t)m * 3 + 0];
        const float qy = new_xyz[(size_t)m * 3 + 1];
        const float qz = new_xyz[(size_t)m * 3 + 2];
        const float r_orig = new_xyz_r[m];
        const int pj = empty ? 0 : sIdxW[j];
        float gx = 0.f, gy = 0.f, gz = 0.f;
        if (!empty) {
            gx = xb[(size_t)pj * 3 + 0] - qx;
            gy = xb[(size_t)pj * 3 + 1] - qy;
            gz = xb[(size_t)pj * 3 + 2] - qz;
        }
        float d2 = gx * gx;
        d2 = d2 + gy * gy;
        d2 = d2 + gz * gz;
        float dist = sqrtf(d2);
        float wt = 1.0f / (1.0f + expf((dist - r_orig) / real_t)); // 1-sigmoid
        out[nf_base + 0 * NS + j] = gx;
        out[nf_base + 1 * NS + j] = gy;
        out[nf_base + 2 * NS + j] = gz;
        wout[(size_t)m * NS + j] = wt;
        iout[(size_t)m * NS + j] = (float)pj;   // f32 buffer; idx exact
    }

    const float* fb = features + (size_t)bb * N_per * C;
    int c0 = 0;
    for (; c0 + 32 <= C; c0 += 32) {
        const int k  = lane & 7;                 // col group (4 channels)
        const int f4 = 4 * (k & 3);              // XOR swizzle
        #pragma unroll
        for (int t = 0; t < 4; ++t) {
            const int r  = 8 * t + (lane >> 3);  // sample slot
            const int pj = empty ? 0 : sIdxW[r];
            float4 v = make_float4(0.f, 0.f, 0.f, 0.f);
            if (!empty) v = *(const float4*)(fb + (size_t)pj * C + c0 + 4 * k);
            const int rs = r ^ f4;
            sT[(4 * k + 0) * TSTRIDE + rs] = v.x;
            sT[(4 * k + 1) * TSTRIDE + rs] = v.y;
            sT[(4 * k + 2) * TSTRIDE + rs] = v.z;
            sT[(4 * k + 3) * TSTRIDE + rs] = v.w;
        }
        // wave-internal LDS dependency: lockstep + lgkmcnt, no barrier
        const int jg = lane & 7;                 // group of 4 samples
        #pragma unroll
        for (int s2 = 0; s2 < 4; ++s2) {
            const int ch = 8 * s2 + (lane >> 3); // channel within pass
            const int jb = (4 * jg) ^ (4 * ((ch >> 2) & 3));
            float4 w = *(const float4*)&sT[ch * TSTRIDE + jb];
            *(float4*)&out[nf_base + (size_t)(3 + c0 + ch) * NS + 4 * jg] = w;
        }
    }
    if (c0 < C) {   // tail for C % 32 != 0 (dead for C=64)
        const int h  = lane >> 5;
        const int pj = empty ? 0 : sIdxW[j];
        const float* frow = fb + (size_t)pj * C;
        for (int c = c0 + h; c < C; c += 2) {
            float v = empty ? 0.f : frow[c];
            out[nf_base + (size_t)(3 + c) * NS + j] = v;
        }
    }
}

// ---------------------------------------------------------------------------
// Single fused kernel.
// Phase 1: per-wave prefix ball-query (first SCAN0 points); dense queries
//          (~93%) write all outputs immediately, barrier-free.
// Phase 2: block-local straggler recovery: for each wave whose query had
//          cnt<NS, all 4 waves rescan disjoint quarter-ranges of the FULL
//          range (4x shorter critical path), in-order LDS merge reproduces
//          exact first-NS semantics, wave 0 writes that query's outputs.
// No workspace, no atomics, no extra dispatches.
// ---------------------------------------------------------------------------
__global__ __launch_bounds__(256) void qgd_fused(
    const float* __restrict__ xyz, const float* __restrict__ new_xyz,
    const float* __restrict__ new_xyz_r, const float* __restrict__ features,
    const float* __restrict__ tdec, float* __restrict__ out,
    int N_per, int M_per, int C, int M_tot)
{
#pragma clang fp contract(off)          // keep d2 < r^2 bit-exact vs numpy
    __shared__ __align__(16) float sBuf[WPB * 32 * TSTRIDE];
    __shared__ int sIdx[WPB][NS];
    __shared__ int sH[WPB][NS];
    __shared__ int sC[WPB];
    __shared__ int sStrag[WPB];
    __shared__ int sM[NS];
    __shared__ int sTot;

    const int lane = threadIdx.x & 63;
    const int wv   = threadIdx.x >> 6;
    const int m    = blockIdx.x * WPB + wv;
    const bool active = (m < M_tot);
    const unsigned long long lt = (1ull << lane) - 1ull;
    const float real_t = 0.1f * tdec[0];

    // ---- phase 1: dense prefix scan + immediate epilogue ----
    int cnt = 0;
    if (active) {
        const int bb = m / M_per;
        const float* xb = xyz + (size_t)bb * N_per * 3;
        const float qx = new_xyz[(size_t)m * 3 + 0];
        const float qy = new_xyz[(size_t)m * 3 + 1];
        const float qz = new_xyz[(size_t)m * 3 + 2];
        const float er  = new_xyz_r[m] + real_t * 5.0f;
        const float er2 = er * er;

        const int scan0 = (SCAN0 < N_per) ? SCAN0 : N_per;
        for (int base = 0; base < scan0; base += 256) {
            float d2k[4];
            #pragma unroll
            for (int k = 0; k < 4; ++k) {
                int p = base + k * 64 + lane;
                int pc = (p < N_per) ? p : (N_per - 1);
                const float* pp = xb + (size_t)pc * 3;
                float dx = pp[0] - qx, dy = pp[1] - qy, dz = pp[2] - qz;
                float d2 = dx * dx;
                d2 = d2 + dy * dy;      // numpy left-fold order
                d2 = d2 + dz * dz;
                d2k[k] = (p < N_per) ? d2 : 1e30f;
            }
            #pragma unroll
            for (int k = 0; k < 4; ++k) {
                bool hit = d2k[k] < er2;    // strict <
                unsigned long long msk = __ballot(hit);
                if (hit) {
                    int slot = cnt + (int)__popcll(msk & lt);
                    if (slot < NS) sIdx[wv][slot] = base + k * 64 + lane;
                }
                cnt += (int)__popcll(msk);  // wave-uniform
            }
            if (cnt >= NS) break;           // wave-uniform
        }

        if (cnt >= NS) {
            write_query(m, bb, /*empty=*/false, lane, sIdx[wv],
                        sBuf + wv * (32 * TSTRIDE),
                        xyz, new_xyz, new_xyz_r, features, real_t, out,
                        N_per, C, M_tot);
        }
    }
    if (lane == 0) sStrag[wv] = (active && cnt < NS) ? 1 : 0;
    __syncthreads();                     // flags + dense epilogues complete

    // ---- phase 2: block-local straggler recovery ----
    for (int s = 0; s < WPB; ++s) {
        if (!sStrag[s]) continue;        // block-uniform (shared read)
        const int ms = blockIdx.x * WPB + s;
        const int bb = ms / M_per;
        const float* xb = xyz + (size_t)bb * N_per * 3;
        const float qx = new_xyz[(size_t)ms * 3 + 0];
        const float qy = new_xyz[(size_t)ms * 3 + 1];
        const float qz = new_xyz[(size_t)ms * 3 + 2];
        const float er  = new_xyz_r[ms] + real_t * 5.0f;
        const float er2 = er * er;

        const int rb = (int)(((long long)N_per * wv) / WPB);
        const int re = (int)(((long long)N_per * (wv + 1)) / WPB);

        int c2 = 0;
        for (int base = rb; base < re; base += 256) {
            float d2k[4];
            #pragma unroll
            for (int k = 0; k < 4; ++k) {
                int p = base + k * 64 + lane;
                int pc = (p < re) ? p : (re - 1);
                const float* pp = xb + (size_t)pc * 3;
                float dx = pp[0] - qx, dy = pp[1] - qy, dz = pp[2] - qz;
                float d2 = dx * dx;
                d2 = d2 + dy * dy;
                d2 = d2 + dz * dz;
                d2k[k] = (p < re) ? d2 : 1e30f;
            }
            #pragma unroll
            for (int k = 0; k < 4; ++k) {
                bool hit = d2k[k] < er2;
                unsigned long long msk = __ballot(hit);
                if (hit) {
                    int slot = c2 + (int)__popcll(msk & lt);
                    if (slot < NS) sH[wv][slot] = base + k * 64 + lane;
                }
                c2 += (int)__popcll(msk);
            }
            if (c2 >= NS) break;
        }
        if (lane == 0) sC[wv] = (c2 < NS) ? c2 : NS;
        __syncthreads();                 // sH/sC ready

        if (threadIdx.x < NS) {          // in-order merge (wave 0 lanes)
            const int j  = threadIdx.x;
            const int q0 = sC[0], q1 = sC[1], q2 = sC[2], q3 = sC[3];
            const int o1 = q0, o2 = q0 + q1, o3 = o2 + q2;
            const int tot = o3 + q3;
            int v = 0;
            if (j < tot) {
                if      (j >= o3) v = sH[3][j - o3];
                else if (j >= o2) v = sH[2][j - o2];
                else if (j >= o1) v = sH[1][j - o1];
                else              v = sH[0][j];
            }
            int first = 0;
            if      (q0 > 0) first = sH[0][0];
            else if (q1 > 0) first = sH[1][0];
            else if (q2 > 0) first = sH[2][0];
            else if (q3 > 0) first = sH[3][0];
            sM[j] = (tot == 0) ? 0 : ((j < tot) ? v : first);
            if (j == 0) sTot = tot;
        }
        __syncthreads();                 // sM/sTot ready

        if (wv == 0) {
            write_query(ms, bb, /*empty=*/(sTot == 0), lane, sM, sBuf,
                        xyz, new_xyz, new_xyz_r, features, real_t, out,
                        N_per, C, M_tot);
        }
        __syncthreads();                 // tiles reusable for next straggler
    }
}

extern "C" void kernel_launch(void* const* d_in, const int* in_sizes, int n_in,
                              void* d_out, int out_size, void* d_ws, size_t ws_size,
                              hipStream_t stream) {
    const float* xyz       = (const float*)d_in[0];
    const float* new_xyz   = (const float*)d_in[2];
    const float* new_xyz_r = (const float*)d_in[3];
    const float* features  = (const float*)d_in[5];
    const float* tdec      = (const float*)d_in[6];

    const int B     = in_sizes[1];
    const int N_tot = in_sizes[0] / 3;
    const int M_tot = in_sizes[2] / 3;
    const int C     = in_sizes[5] / N_tot;
    const int N_per = N_tot / B;
    const int M_per = M_tot / B;

    const int blocks = (M_tot + WPB - 1) / WPB;
    qgd_fused<<<blocks, 256, 0, stream>>>(xyz, new_xyz, new_xyz_r, features,
                                          tdec, (float*)d_out,
                                          N_per, M_per, C, M_tot);
}